// Round 6
// baseline (137.054 us; speedup 1.0000x reference)
//
#include <hip/hip_runtime.h>
#include <stdint.h>

#define BATCH 8192
#define DIM 256
#define NSPLIT 16
#define BM 256
#define BN 64
#define COLS_PER_SPLIT (BATCH / NSPLIT)   // 512
#define NTILES (COLS_PER_SPLIT / BN)      // 8
#define NROWBLK (BATCH / BM)              // 32
#define LOG2E 1.4426950408889634f
#define LN2   0.6931471805599453f

typedef float floatx4 __attribute__((ext_vector_type(4)));
typedef float floatx2 __attribute__((ext_vector_type(2)));
typedef int intx4 __attribute__((ext_vector_type(4)));
typedef int intx8 __attribute__((ext_vector_type(8)));

__device__ __forceinline__ float fast_exp2(float x) {
#if __has_builtin(__builtin_amdgcn_exp2f)
    return __builtin_amdgcn_exp2f(x);
#else
    return exp2f(x);
#endif
}

// ---------------------------------------------------------------------------
// Prep: fp32 -> fp8 e4m3 (HW cvt_pk) into f8f6f4 fragment layout (same as R5).
// Per 16-row tile (4 KB): byte = tile*4096 + kstep*2048 + half*1024
//                                + (kgroup*16+row)*16 + (k&15).
// Also t2[j], diag[i] in fp32 (exact), and zeroes the atomic-epilogue
// counters/accumulator (runs every call -> re-poison safe).
// ---------------------------------------------------------------------------
__global__ __launch_bounds__(256) void prep_kernel(
        const float* __restrict__ pred, const float* __restrict__ target,
        uint8_t* __restrict__ Ap, uint8_t* __restrict__ Bp,
        float* __restrict__ t2, float* __restrict__ diag,
        int* __restrict__ cnt, int* __restrict__ cnt2,
        float* __restrict__ gacc) {
    __shared__ __align__(16) uint8_t ldsA[4096];
    __shared__ __align__(16) uint8_t ldsB[4096];
    const int t = threadIdx.x;
    const int r = t >> 4, c = t & 15;
    const int rt = blockIdx.x;
    const int row = rt * 16 + r;

    if (rt == 0) {
        if (t < NROWBLK) cnt[t] = 0;
        if (t == NROWBLK) *cnt2 = 0;
        if (t == NROWBLK + 1) *gacc = 0.0f;
    }

    float dsum = 0.f, tsum = 0.f;
#pragma unroll
    for (int q = 0; q < 4; ++q) {
        const int k0 = q * 64 + c * 4;
        const float4 p4 = *(const float4*)(pred + (size_t)row * DIM + k0);
        const float4 t4 = *(const float4*)(target + (size_t)row * DIM + k0);
        dsum += p4.x * t4.x + p4.y * t4.y + p4.z * t4.z + p4.w * t4.w;
        tsum += t4.x * t4.x + t4.y * t4.y + t4.z * t4.z + t4.w * t4.w;
        const int kstep  = k0 >> 7;
        const int kgroup = (k0 >> 5) & 3;
        const int half   = (k0 >> 4) & 1;
        const int b      = k0 & 15;
        const int off = kstep * 2048 + half * 1024 + (kgroup * 16 + r) * 16 + b;
        int pp = __builtin_amdgcn_cvt_pk_fp8_f32(p4.x, p4.y, 0, false);
        pp     = __builtin_amdgcn_cvt_pk_fp8_f32(p4.z, p4.w, pp, true);
        int tt = __builtin_amdgcn_cvt_pk_fp8_f32(t4.x, t4.y, 0, false);
        tt     = __builtin_amdgcn_cvt_pk_fp8_f32(t4.z, t4.w, tt, true);
        *(int*)(ldsA + off) = pp;
        *(int*)(ldsB + off) = tt;
    }
#pragma unroll
    for (int mask = 1; mask < 16; mask <<= 1) {
        dsum += __shfl_xor(dsum, mask);
        tsum += __shfl_xor(tsum, mask);
    }
    if (c == 0) { diag[row] = dsum; t2[row] = tsum; }
    __syncthreads();

    const size_t base = (size_t)rt * 4096;
    const uint4 va = *(const uint4*)(ldsA + t * 16);
    const uint4 vb = *(const uint4*)(ldsB + t * 16);
    *(uint4*)(Ap + base + (size_t)t * 16) = va;
    *(uint4*)(Bp + base + (size_t)t * 16) = vb;
}

// ---------------------------------------------------------------------------
// Main v6 (MX-fp8, fused finish): 256 rows x 512 cols per WG; mt=4, BN=64
// (nt=4, 8 tiles -> half the barriers of v5). A frags resident (64 VGPR).
// LDS dbuf 2x16 KB, one barrier/tile, next tile pre-staged. Epilogue:
// per-slot fixed log2 offset + exp2 accumulate. After partials: split-K
// atomic-counter finish — last block per rowBlk lse-combines 16 splits for
// its 256 rows, block-reduces, atomic-accumulates; global last writes out.
// ---------------------------------------------------------------------------
__global__ __launch_bounds__(256, 2) void main_kernel(
        const uint8_t* __restrict__ Ap, const uint8_t* __restrict__ Bp,
        const float* __restrict__ t2, const float* __restrict__ diag,
        const float* __restrict__ sigma, float2* __restrict__ partials,
        int* __restrict__ cnt, int* __restrict__ cnt2,
        float* __restrict__ gacc, float* __restrict__ out) {
    __shared__ __align__(16) uint8_t ldsB[2][BN * DIM];   // 2 x 16 KB

    const int lane   = threadIdx.x & 63;
    const int wave   = threadIdx.x >> 6;
    const int rowBlk = blockIdx.x;    // 0..31
    const int split  = blockIdx.y;    // 0..15

    const float sg = sigma[0];
    const float nv = sg * sg;
    const float inv_nv = 1.0f / nv;
    const float c1 = LOG2E * inv_nv;        // logits(log2) = dot*c1 + t2*c2
    const float c2 = -0.5f * c1;
    const float floor2 = -108.0f * c1;      // overflow-safe offset floor

    // resident A fragments: rows rowBlk*256 + wave*64 + mt*16 + (lane&15)
    intx8 afrag[4][2];
#pragma unroll
    for (int mt = 0; mt < 4; ++mt) {
        const uint8_t* base = Ap + (size_t)(rowBlk * 16 + wave * 4 + mt) * 4096 + lane * 16;
#pragma unroll
        for (int ks = 0; ks < 2; ++ks) {
            const intx4 lo = *(const intx4*)(base + ks * 2048);
            const intx4 hi = *(const intx4*)(base + ks * 2048 + 1024);
            afrag[mt][ks] = (intx8){lo.x, lo.y, lo.z, lo.w, hi.x, hi.y, hi.z, hi.w};
        }
    }

    floatx2 m2[4][2], l2[4][2];
#pragma unroll
    for (int mt = 0; mt < 4; ++mt)
#pragma unroll
        for (int rp = 0; rp < 2; ++rp) {
            m2[mt][rp] = (floatx2){floor2, floor2};
            l2[mt][rp] = (floatx2){0.f, 0.f};
        }

    // stage tile 0 (16 KB = four contiguous 16-col fragment tiles)
    {
        const int j0 = split * COLS_PER_SPLIT;
        const char* gbase = (const char*)(Bp + (size_t)(j0 >> 4) * 4096);
#pragma unroll
        for (int q = 0; q < 4; ++q) {
            const int ch = wave * 4 + q;                // 0..15 x 1 KB
            __builtin_amdgcn_global_load_lds(
                (const __attribute__((address_space(1))) void*)(gbase + ch * 1024 + (size_t)lane * 16),
                (__attribute__((address_space(3))) void*)((char*)ldsB[0] + ch * 1024),
                16, 0, 0);
        }
    }
    __syncthreads();

    for (int ct = 0; ct < NTILES; ++ct) {
        const uint8_t* cur = ldsB[ct & 1];
        const int j0 = split * COLS_PER_SPLIT + ct * BN;

        // stage NEXT tile into the other buffer (read-complete since the
        // previous barrier); drained at this tile's barrier.
        if (ct + 1 < NTILES) {
            const char* gbase = (const char*)(Bp + (size_t)((j0 + BN) >> 4) * 4096);
            char* lbase = (char*)ldsB[(ct + 1) & 1];
#pragma unroll
            for (int q = 0; q < 4; ++q) {
                const int ch = wave * 4 + q;
                __builtin_amdgcn_global_load_lds(
                    (const __attribute__((address_space(1))) void*)(gbase + ch * 1024 + (size_t)lane * 16),
                    (__attribute__((address_space(3))) void*)(lbase + ch * 1024),
                    16, 0, 0);
            }
        }

        // t2 loads issued early; consumed after K-loop
        float t2v[4];
#pragma unroll
        for (int nt = 0; nt < 4; ++nt)
            t2v[nt] = t2[j0 + nt * 16 + (lane & 15)];

        floatx4 acc[4][4];
#pragma unroll
        for (int mt = 0; mt < 4; ++mt)
#pragma unroll
            for (int nt = 0; nt < 4; ++nt)
                acc[mt][nt] = (floatx4){0.f, 0.f, 0.f, 0.f};

#pragma unroll
        for (int ks = 0; ks < 2; ++ks) {
#pragma unroll
            for (int nt = 0; nt < 4; ++nt) {
                const uint8_t* bb = cur + nt * 4096 + ks * 2048 + lane * 16;
                const intx4 lo = *(const intx4*)(bb);
                const intx4 hi = *(const intx4*)(bb + 1024);
                const intx8 bfrag = (intx8){lo.x, lo.y, lo.z, lo.w, hi.x, hi.y, hi.z, hi.w};
#pragma unroll
                for (int mt = 0; mt < 4; ++mt) {
                    acc[mt][nt] = __builtin_amdgcn_mfma_scale_f32_16x16x128_f8f6f4(
                        afrag[mt][ks], bfrag, acc[mt][nt],
                        0, 0,          // cbsz=FP8(e4m3), blgp=FP8(e4m3)
                        0, 127,        // scale A: opsel 0, E8M0 127 = 1.0
                        0, 127);       // scale B
                }
            }
        }

        float tvc[4];
#pragma unroll
        for (int nt = 0; nt < 4; ++nt) tvc[nt] = t2v[nt] * c2;

        if (ct == 0) {
#pragma unroll
            for (int mt = 0; mt < 4; ++mt)
#pragma unroll
                for (int rp = 0; rp < 2; ++rp) {
                    floatx2 v[4];
#pragma unroll
                    for (int nt = 0; nt < 4; ++nt)
                        v[nt] = (floatx2){acc[mt][nt][2 * rp], acc[mt][nt][2 * rp + 1]} * c1 + tvc[nt];
                    floatx2 mm = __builtin_elementwise_max(
                        __builtin_elementwise_max(v[0], v[1]),
                        __builtin_elementwise_max(v[2], v[3]));
                    mm = __builtin_elementwise_max(mm, (floatx2){floor2, floor2});
                    m2[mt][rp] = mm;
                    floatx2 s = (floatx2){0.f, 0.f};
#pragma unroll
                    for (int nt = 0; nt < 4; ++nt) {
                        s.x += fast_exp2(v[nt].x - mm.x);
                        s.y += fast_exp2(v[nt].y - mm.y);
                    }
                    l2[mt][rp] = s;
                }
        } else {
#pragma unroll
            for (int mt = 0; mt < 4; ++mt)
#pragma unroll
                for (int rp = 0; rp < 2; ++rp) {
                    const floatx2 mm = m2[mt][rp];
                    floatx2 s = l2[mt][rp];
#pragma unroll
                    for (int nt = 0; nt < 4; ++nt) {
                        const floatx2 v = (floatx2){acc[mt][nt][2 * rp], acc[mt][nt][2 * rp + 1]} * c1
                                          + (tvc[nt] - mm);
                        s.x += fast_exp2(v.x);
                        s.y += fast_exp2(v.y);
                    }
                    l2[mt][rp] = s;
                }
        }

        __syncthreads();   // one barrier/tile: LDS-read fence + staging drain
    }

    // combine the 16 column-slot lanes per row; write per-split partials
#pragma unroll
    for (int mt = 0; mt < 4; ++mt)
#pragma unroll
        for (int rp = 0; rp < 2; ++rp)
#pragma unroll
            for (int z = 0; z < 2; ++z) {
                float m = m2[mt][rp][z];
                float l = l2[mt][rp][z];
#pragma unroll
                for (int mask = 1; mask < 16; mask <<= 1) {
                    const float mo = __shfl_xor(m, mask);
                    const float lo = __shfl_xor(l, mask);
                    const float mn = fmaxf(m, mo);
                    l = l * fast_exp2(m - mn) + lo * fast_exp2(mo - mn);
                    m = mn;
                }
                if ((lane & 15) == 0) {
                    const int r  = rp * 2 + z;
                    const int rw = rowBlk * BM + wave * 64 + mt * 16 + (lane >> 4) * 4 + r;
                    partials[(size_t)split * BATCH + rw] = make_float2(m, l);
                }
            }

    // ---- fused split-K finish (atomic-counter epilogue) ----
    __threadfence();   // release: partials visible device-wide before count
    __shared__ int isLast;
    if (threadIdx.x == 0)
        isLast = (atomicAdd(&cnt[rowBlk], 1) == NSPLIT - 1);
    __syncthreads();
    if (!isLast) return;

    __threadfence();   // acquire: see all splits' partials
    const int tid = threadIdx.x;
    const int row = rowBlk * BM + tid;   // BM == blockDim == 256
    float2 p[NSPLIT];
    float m = -__builtin_inff();
#pragma unroll
    for (int s = 0; s < NSPLIT; ++s) {
        p[s] = partials[(size_t)s * BATCH + row];
        m = fmaxf(m, p[s].x);
    }
    float L = 0.0f;
#pragma unroll
    for (int s = 0; s < NSPLIT; ++s)
        L += p[s].y * fast_exp2(p[s].x - m);
    const float lse_nat = LN2 * (m + __log2f(L));
    const float d = (diag[row] - 0.5f * t2[row]) * inv_nv;

    float* red = (float*)ldsB;           // reuse LDS (loop done, post-barrier)
    red[tid] = lse_nat - d;
    __syncthreads();
    for (int s = 128; s > 0; s >>= 1) {
        if (tid < s) red[tid] += red[tid + s];
        __syncthreads();
    }
    if (tid == 0) {
        atomicAdd(gacc, red[0]);
        __threadfence();
        if (atomicAdd(cnt2, 1) == NROWBLK - 1) {
            const float tot = atomicAdd(gacc, 0.0f);   // RMW read: fresh
            out[0] = 2.0f * nv * tot / (float)BATCH;
        }
    }
}

extern "C" void kernel_launch(void* const* d_in, const int* in_sizes, int n_in,
                              void* d_out, int out_size, void* d_ws, size_t ws_size,
                              hipStream_t stream) {
    const float* pred   = (const float*)d_in[0];
    const float* target = (const float*)d_in[1];
    const float* sigma  = (const float*)d_in[2];
    float* out = (float*)d_out;

    char* ws = (char*)d_ws;
    uint8_t* Ap   = (uint8_t*)(ws);                                    // 2 MB
    uint8_t* Bp   = (uint8_t*)(ws + (size_t)BATCH * DIM);              // 2 MB
    float* t2     = (float*)(ws + (size_t)BATCH * DIM * 4);            // 32 KB
    float* diag   = (float*)(ws + (size_t)BATCH * DIM * 4 + BATCH * 4);
    float2* parts = (float2*)(ws + (size_t)BATCH * DIM * 4 + (size_t)BATCH * 8);
    char* tail    = ws + (size_t)BATCH * DIM * 4 + (size_t)BATCH * 8
                       + (size_t)NSPLIT * BATCH * 8;
    int* cnt      = (int*)tail;                       // 32 ints
    int* cnt2     = (int*)(tail + 128);
    float* gacc   = (float*)(tail + 192);

    prep_kernel<<<BATCH / 16, 256, 0, stream>>>(pred, target, Ap, Bp, t2, diag,
                                                cnt, cnt2, gacc);
    main_kernel<<<dim3(NROWBLK, NSPLIT), 256, 0, stream>>>(Ap, Bp, t2, diag,
                                                           sigma, parts,
                                                           cnt, cnt2, gacc, out);
}

// Round 7
// 93.084 us; speedup vs baseline: 1.4724x; 1.4724x over previous
//
#include <hip/hip_runtime.h>
#include <stdint.h>

#define BATCH 8192
#define DIM 256
#define NSPLIT 16
#define BM 256
#define BN 64
#define COLS_PER_SPLIT (BATCH / NSPLIT)   // 512
#define NTILES (COLS_PER_SPLIT / BN)      // 8
#define LOG2E 1.4426950408889634f
#define LN2   0.6931471805599453f

typedef float floatx4 __attribute__((ext_vector_type(4)));
typedef float floatx2 __attribute__((ext_vector_type(2)));
typedef int intx4 __attribute__((ext_vector_type(4)));
typedef int intx8 __attribute__((ext_vector_type(8)));

__device__ __forceinline__ float fast_exp2(float x) {
#if __has_builtin(__builtin_amdgcn_exp2f)
    return __builtin_amdgcn_exp2f(x);
#else
    return exp2f(x);
#endif
}

// ---------------------------------------------------------------------------
// Prep: fp32 -> fp8 e4m3 (HW cvt_pk) into f8f6f4 fragment layout.
// Per 16-row tile (4 KB): byte = tile*4096 + kstep*2048 + half*1024
//                                + (kgroup*16+row)*16 + (k&15).
// Also t2[j], diag[i] in fp32 (exact).
// ---------------------------------------------------------------------------
__global__ __launch_bounds__(256) void prep_kernel(
        const float* __restrict__ pred, const float* __restrict__ target,
        uint8_t* __restrict__ Ap, uint8_t* __restrict__ Bp,
        float* __restrict__ t2, float* __restrict__ diag) {
    __shared__ __align__(16) uint8_t ldsA[4096];
    __shared__ __align__(16) uint8_t ldsB[4096];
    const int t = threadIdx.x;
    const int r = t >> 4, c = t & 15;
    const int rt = blockIdx.x;
    const int row = rt * 16 + r;

    float dsum = 0.f, tsum = 0.f;
#pragma unroll
    for (int q = 0; q < 4; ++q) {
        const int k0 = q * 64 + c * 4;
        const float4 p4 = *(const float4*)(pred + (size_t)row * DIM + k0);
        const float4 t4 = *(const float4*)(target + (size_t)row * DIM + k0);
        dsum += p4.x * t4.x + p4.y * t4.y + p4.z * t4.z + p4.w * t4.w;
        tsum += t4.x * t4.x + t4.y * t4.y + t4.z * t4.z + t4.w * t4.w;
        const int kstep  = k0 >> 7;
        const int kgroup = (k0 >> 5) & 3;
        const int half   = (k0 >> 4) & 1;
        const int b      = k0 & 15;
        const int off = kstep * 2048 + half * 1024 + (kgroup * 16 + r) * 16 + b;
        int pp = __builtin_amdgcn_cvt_pk_fp8_f32(p4.x, p4.y, 0, false);
        pp     = __builtin_amdgcn_cvt_pk_fp8_f32(p4.z, p4.w, pp, true);
        int tt = __builtin_amdgcn_cvt_pk_fp8_f32(t4.x, t4.y, 0, false);
        tt     = __builtin_amdgcn_cvt_pk_fp8_f32(t4.z, t4.w, tt, true);
        *(int*)(ldsA + off) = pp;
        *(int*)(ldsB + off) = tt;
    }
#pragma unroll
    for (int mask = 1; mask < 16; mask <<= 1) {
        dsum += __shfl_xor(dsum, mask);
        tsum += __shfl_xor(tsum, mask);
    }
    if (c == 0) { diag[row] = dsum; t2[row] = tsum; }
    __syncthreads();

    const size_t base = (size_t)rt * 4096;
    const uint4 va = *(const uint4*)(ldsA + t * 16);
    const uint4 vb = *(const uint4*)(ldsB + t * 16);
    *(uint4*)(Ap + base + (size_t)t * 16) = va;
    *(uint4*)(Bp + base + (size_t)t * 16) = vb;
}

// ---------------------------------------------------------------------------
// Main v7 (MX-fp8): 256 rows x 512 cols per WG; mt=4 (64 rows/wave), BN=64
// (nt=4 -> 8 tiles, half the barriers of BN=32). A frags resident (64 VGPR).
// LDS dbuf 2x16 KB, one barrier/tile, next tile pre-staged before the K-loop.
// NO device-scope fences in this kernel (R6 lesson: per-block __threadfence
// on multi-XCD = L2 writeback per block = ~56 us of stall). Finish kernels
// are separate and fence-free (stream order provides visibility).
// ---------------------------------------------------------------------------
__global__ __launch_bounds__(256, 2) void main_kernel(
        const uint8_t* __restrict__ Ap, const uint8_t* __restrict__ Bp,
        const float* __restrict__ t2, const float* __restrict__ sigma,
        float2* __restrict__ partials) {
    __shared__ __align__(16) uint8_t ldsB[2][BN * DIM];   // 2 x 16 KB

    const int lane   = threadIdx.x & 63;
    const int wave   = threadIdx.x >> 6;
    const int rowBlk = blockIdx.x;    // 0..31
    const int split  = blockIdx.y;    // 0..15

    const float sg = sigma[0];
    const float inv_nv = 1.0f / (sg * sg);
    const float c1 = LOG2E * inv_nv;        // logits(log2) = dot*c1 + t2*c2
    const float c2 = -0.5f * c1;
    const float floor2 = -108.0f * c1;      // overflow-safe offset floor

    // resident A fragments: rows rowBlk*256 + wave*64 + mt*16 + (lane&15)
    intx8 afrag[4][2];
#pragma unroll
    for (int mt = 0; mt < 4; ++mt) {
        const uint8_t* base = Ap + (size_t)(rowBlk * 16 + wave * 4 + mt) * 4096 + lane * 16;
#pragma unroll
        for (int ks = 0; ks < 2; ++ks) {
            const intx4 lo = *(const intx4*)(base + ks * 2048);
            const intx4 hi = *(const intx4*)(base + ks * 2048 + 1024);
            afrag[mt][ks] = (intx8){lo.x, lo.y, lo.z, lo.w, hi.x, hi.y, hi.z, hi.w};
        }
    }

    floatx2 m2[4][2], l2[4][2];
#pragma unroll
    for (int mt = 0; mt < 4; ++mt)
#pragma unroll
        for (int rp = 0; rp < 2; ++rp) {
            m2[mt][rp] = (floatx2){floor2, floor2};
            l2[mt][rp] = (floatx2){0.f, 0.f};
        }

    // stage tile 0 (16 KB = four contiguous 16-col fragment tiles)
    {
        const int j0 = split * COLS_PER_SPLIT;
        const char* gbase = (const char*)(Bp + (size_t)(j0 >> 4) * 4096);
#pragma unroll
        for (int q = 0; q < 4; ++q) {
            const int ch = wave * 4 + q;                // 0..15 x 1 KB
            __builtin_amdgcn_global_load_lds(
                (const __attribute__((address_space(1))) void*)(gbase + ch * 1024 + (size_t)lane * 16),
                (__attribute__((address_space(3))) void*)((char*)ldsB[0] + ch * 1024),
                16, 0, 0);
        }
    }
    __syncthreads();

    for (int ct = 0; ct < NTILES; ++ct) {
        const uint8_t* cur = ldsB[ct & 1];
        const int j0 = split * COLS_PER_SPLIT + ct * BN;

        // stage NEXT tile into the other buffer (read-complete since the
        // previous barrier); drained at this tile's barrier.
        if (ct + 1 < NTILES) {
            const char* gbase = (const char*)(Bp + (size_t)((j0 + BN) >> 4) * 4096);
            char* lbase = (char*)ldsB[(ct + 1) & 1];
#pragma unroll
            for (int q = 0; q < 4; ++q) {
                const int ch = wave * 4 + q;
                __builtin_amdgcn_global_load_lds(
                    (const __attribute__((address_space(1))) void*)(gbase + ch * 1024 + (size_t)lane * 16),
                    (__attribute__((address_space(3))) void*)(lbase + ch * 1024),
                    16, 0, 0);
            }
        }

        // t2 loads issued early; consumed after K-loop
        float t2v[4];
#pragma unroll
        for (int nt = 0; nt < 4; ++nt)
            t2v[nt] = t2[j0 + nt * 16 + (lane & 15)];

        floatx4 acc[4][4];
#pragma unroll
        for (int mt = 0; mt < 4; ++mt)
#pragma unroll
            for (int nt = 0; nt < 4; ++nt)
                acc[mt][nt] = (floatx4){0.f, 0.f, 0.f, 0.f};

#pragma unroll
        for (int ks = 0; ks < 2; ++ks) {
#pragma unroll
            for (int nt = 0; nt < 4; ++nt) {
                const uint8_t* bb = cur + nt * 4096 + ks * 2048 + lane * 16;
                const intx4 lo = *(const intx4*)(bb);
                const intx4 hi = *(const intx4*)(bb + 1024);
                const intx8 bfrag = (intx8){lo.x, lo.y, lo.z, lo.w, hi.x, hi.y, hi.z, hi.w};
#pragma unroll
                for (int mt = 0; mt < 4; ++mt) {
                    acc[mt][nt] = __builtin_amdgcn_mfma_scale_f32_16x16x128_f8f6f4(
                        afrag[mt][ks], bfrag, acc[mt][nt],
                        0, 0,          // cbsz=FP8(e4m3), blgp=FP8(e4m3)
                        0, 127,        // scale A: opsel 0, E8M0 127 = 1.0
                        0, 127);       // scale B
                }
            }
        }

        float tvc[4];
#pragma unroll
        for (int nt = 0; nt < 4; ++nt) tvc[nt] = t2v[nt] * c2;

        if (ct == 0) {
#pragma unroll
            for (int mt = 0; mt < 4; ++mt)
#pragma unroll
                for (int rp = 0; rp < 2; ++rp) {
                    floatx2 v[4];
#pragma unroll
                    for (int nt = 0; nt < 4; ++nt)
                        v[nt] = (floatx2){acc[mt][nt][2 * rp], acc[mt][nt][2 * rp + 1]} * c1 + tvc[nt];
                    floatx2 mm = __builtin_elementwise_max(
                        __builtin_elementwise_max(v[0], v[1]),
                        __builtin_elementwise_max(v[2], v[3]));
                    mm = __builtin_elementwise_max(mm, (floatx2){floor2, floor2});
                    m2[mt][rp] = mm;
                    floatx2 s = (floatx2){0.f, 0.f};
#pragma unroll
                    for (int nt = 0; nt < 4; ++nt) {
                        s.x += fast_exp2(v[nt].x - mm.x);
                        s.y += fast_exp2(v[nt].y - mm.y);
                    }
                    l2[mt][rp] = s;
                }
        } else {
#pragma unroll
            for (int mt = 0; mt < 4; ++mt)
#pragma unroll
                for (int rp = 0; rp < 2; ++rp) {
                    const floatx2 mm = m2[mt][rp];
                    floatx2 s = l2[mt][rp];
#pragma unroll
                    for (int nt = 0; nt < 4; ++nt) {
                        const floatx2 v = (floatx2){acc[mt][nt][2 * rp], acc[mt][nt][2 * rp + 1]} * c1
                                          + (tvc[nt] - mm);
                        s.x += fast_exp2(v.x);
                        s.y += fast_exp2(v.y);
                    }
                    l2[mt][rp] = s;
                }
        }

        __syncthreads();   // one barrier/tile: LDS-read fence + staging drain
    }

    // combine the 16 column-slot lanes per row; write per-split partials
#pragma unroll
    for (int mt = 0; mt < 4; ++mt)
#pragma unroll
        for (int rp = 0; rp < 2; ++rp)
#pragma unroll
            for (int z = 0; z < 2; ++z) {
                float m = m2[mt][rp][z];
                float l = l2[mt][rp][z];
#pragma unroll
                for (int mask = 1; mask < 16; mask <<= 1) {
                    const float mo = __shfl_xor(m, mask);
                    const float lo = __shfl_xor(l, mask);
                    const float mn = fmaxf(m, mo);
                    l = l * fast_exp2(m - mn) + lo * fast_exp2(mo - mn);
                    m = mn;
                }
                if ((lane & 15) == 0) {
                    const int r  = rp * 2 + z;
                    const int rw = rowBlk * BM + wave * 64 + mt * 16 + (lane >> 4) * 4 + r;
                    partials[(size_t)split * BATCH + rw] = make_float2(m, l);
                }
            }
}

// ---------------------------------------------------------------------------
// Finish stage 1: 32 WGs; one row per thread; per-row lse combine + block sum.
// ---------------------------------------------------------------------------
__global__ __launch_bounds__(256) void finish1_kernel(
        const float2* __restrict__ partials, const float* __restrict__ t2,
        const float* __restrict__ diag, const float* __restrict__ sigma,
        float* __restrict__ bsum) {
    __shared__ float red[256];
    const int tid = threadIdx.x;
    const int row = blockIdx.x * 256 + tid;
    const float sg = sigma[0];
    const float inv_nv = 1.0f / (sg * sg);

    float2 p[NSPLIT];
    float m = -__builtin_inff();
#pragma unroll
    for (int s = 0; s < NSPLIT; ++s) {
        p[s] = partials[(size_t)s * BATCH + row];
        m = fmaxf(m, p[s].x);
    }
    float L = 0.0f;
#pragma unroll
    for (int s = 0; s < NSPLIT; ++s)
        L += p[s].y * fast_exp2(p[s].x - m);
    const float lse_nat = LN2 * (m + __log2f(L));
    const float d = (diag[row] - 0.5f * t2[row]) * inv_nv;
    red[tid] = lse_nat - d;
    __syncthreads();
    for (int s = 128; s > 0; s >>= 1) {
        if (tid < s) red[tid] += red[tid + s];
        __syncthreads();
    }
    if (tid == 0) bsum[blockIdx.x] = red[0];
}

// ---------------------------------------------------------------------------
// Finish stage 2: reduce 32 block sums, scale by 2*sigma^2 / BATCH.
// ---------------------------------------------------------------------------
__global__ __launch_bounds__(64) void finish2_kernel(
        const float* __restrict__ bsum, const float* __restrict__ sigma,
        float* __restrict__ out) {
    const int tid = threadIdx.x;
    float v = (tid < 32) ? bsum[tid] : 0.0f;
#pragma unroll
    for (int mask = 32; mask > 0; mask >>= 1)
        v += __shfl_xor(v, mask);
    if (tid == 0) {
        const float nv = sigma[0] * sigma[0];
        out[0] = 2.0f * nv * v / (float)BATCH;
    }
}

extern "C" void kernel_launch(void* const* d_in, const int* in_sizes, int n_in,
                              void* d_out, int out_size, void* d_ws, size_t ws_size,
                              hipStream_t stream) {
    const float* pred   = (const float*)d_in[0];
    const float* target = (const float*)d_in[1];
    const float* sigma  = (const float*)d_in[2];
    float* out = (float*)d_out;

    char* ws = (char*)d_ws;
    uint8_t* Ap   = (uint8_t*)(ws);                                    // 2 MB
    uint8_t* Bp   = (uint8_t*)(ws + (size_t)BATCH * DIM);              // 2 MB
    float* t2     = (float*)(ws + (size_t)BATCH * DIM * 4);            // 32 KB
    float* diag   = (float*)(ws + (size_t)BATCH * DIM * 4 + BATCH * 4);
    float2* parts = (float2*)(ws + (size_t)BATCH * DIM * 4 + (size_t)BATCH * 8);
    float* bsum   = (float*)(ws + (size_t)BATCH * DIM * 4 + (size_t)BATCH * 8
                             + (size_t)NSPLIT * BATCH * 8);

    prep_kernel<<<BATCH / 16, 256, 0, stream>>>(pred, target, Ap, Bp, t2, diag);
    main_kernel<<<dim3(BATCH / BM, NSPLIT), 256, 0, stream>>>(Ap, Bp, t2, sigma, parts);
    finish1_kernel<<<BATCH / 256, 256, 0, stream>>>(parts, t2, diag, sigma, bsum);
    finish2_kernel<<<1, 64, 0, stream>>>(bsum, sigma, out);
}